// Round 6
// baseline (506.866 us; speedup 1.0000x reference)
//
#include <hip/hip_runtime.h>
#include <hip/hip_cooperative_groups.h>

// RhythmNetLoss: out = mean(|r - t|) + 100 * mean(|g - mean(g)|)
// Inputs: 3x float32 [4096,4096]. Output: 1x float32 scalar.
//
// R3 lesson: pass1 dropped to 48.9us (4.1 TB/s effective) but total stuck at
// 198.7 -> the other 3 dispatches + launch ramps dominate (Occupancy 42% =
// ramp-heavy short kernels). Fix: single persistent cooperative kernel with
// grid.sync() between phases. No dispatch gaps; phase2 runs while g is L3-hot.
// (R4/R5: broker timeouts, never ran — resubmitted unchanged.)
//
// ws layout (doubles): [0..nblk) = sum|r-t| partials, [nblk..2nblk) = sum(g)
// partials, [2nblk..3nblk) = sum|g-m| partials.

namespace cg = cooperative_groups;

typedef float f32x4 __attribute__((ext_vector_type(4)));

#define LAMBD 100.0
#define BLOCK 256
#define PT 8                  // float4s per thread per tile
#define TILE (BLOCK * PT)     // 2048 float4 = 32 KiB per stream per tile

__device__ __forceinline__ int swizzle_tile(int tile, int ntiles) {
    if ((ntiles & 7) == 0) {           // bijective XCD swizzle
        int nx = ntiles >> 3;
        return (tile & 7) * nx + (tile >> 3);
    }
    return tile;
}

__global__ void __launch_bounds__(BLOCK, 8)
fused_kernel(const f32x4* __restrict__ r, const f32x4* __restrict__ t,
             const f32x4* __restrict__ g, double* __restrict__ ws,
             float* __restrict__ out, int n4, int ntiles, double inv_n) {
    cg::grid_group grid = cg::this_grid();
    __shared__ float  lfa[4], lfb[4];
    __shared__ double lda[8];
    const int nblk = gridDim.x;
    const int tid  = threadIdx.x;

    // ---------------- phase 1: sum|r-t| and sum(g) ----------------
    float s_abs = 0.f, s_g = 0.f;
    for (int tile = blockIdx.x; tile < ntiles; tile += nblk) {
        int swz = swizzle_tile(tile, ntiles);
        long base = (long)swz * TILE + tid;
        if ((long)swz * TILE + TILE <= n4) {
            f32x4 rv[PT], tv[PT], gv[PT];
            #pragma unroll
            for (int k = 0; k < PT; ++k) rv[k] = __builtin_nontemporal_load(&r[base + k * BLOCK]);
            #pragma unroll
            for (int k = 0; k < PT; ++k) tv[k] = __builtin_nontemporal_load(&t[base + k * BLOCK]);
            #pragma unroll
            for (int k = 0; k < PT; ++k) gv[k] = g[base + k * BLOCK];
            #pragma unroll
            for (int k = 0; k < PT; ++k) {
                f32x4 d = rv[k] - tv[k];
                s_abs += fabsf(d.x) + fabsf(d.y) + fabsf(d.z) + fabsf(d.w);
                s_g   += (gv[k].x + gv[k].y) + (gv[k].z + gv[k].w);
            }
        } else {
            for (int k = 0; k < PT; ++k) {
                long i = base + (long)k * BLOCK;
                if (i < n4) {
                    f32x4 rv = r[i], tv = t[i], gv = g[i];
                    s_abs += fabsf(rv.x - tv.x) + fabsf(rv.y - tv.y) +
                             fabsf(rv.z - tv.z) + fabsf(rv.w - tv.w);
                    s_g += (gv.x + gv.y) + (gv.z + gv.w);
                }
            }
        }
    }
    #pragma unroll
    for (int off = 32; off; off >>= 1) {
        s_abs += __shfl_down(s_abs, off);
        s_g   += __shfl_down(s_g, off);
    }
    if ((tid & 63) == 0) { lfa[tid >> 6] = s_abs; lfb[tid >> 6] = s_g; }
    __syncthreads();
    if (tid == 0) {
        float ba = lfa[0] + lfa[1] + lfa[2] + lfa[3];
        float bg = lfb[0] + lfb[1] + lfb[2] + lfb[3];
        ws[blockIdx.x]        = (double)ba;
        ws[nblk + blockIdx.x] = (double)bg;
        __threadfence();
    }
    grid.sync();

    // ---------------- mean(g): every block, redundantly ----------------
    double v = 0.0;
    for (int i = tid; i < nblk; i += BLOCK) v += ws[nblk + i];
    #pragma unroll
    for (int off = 32; off; off >>= 1) v += __shfl_down(v, off);
    if ((tid & 63) == 0) lda[tid >> 6] = v;
    __syncthreads();
    if (tid == 0) lda[4] = (lda[0] + lda[1] + lda[2] + lda[3]) * inv_n;
    __syncthreads();
    const float m = (float)lda[4];

    // ---------------- phase 2: sum|g - m| ----------------
    float s2 = 0.f;
    for (int tile = blockIdx.x; tile < ntiles; tile += nblk) {
        int swz = swizzle_tile(tile, ntiles);
        long base = (long)swz * TILE + tid;
        if ((long)swz * TILE + TILE <= n4) {
            f32x4 gv[PT];
            #pragma unroll
            for (int k = 0; k < PT; ++k) gv[k] = g[base + k * BLOCK];
            #pragma unroll
            for (int k = 0; k < PT; ++k) {
                s2 += fabsf(gv[k].x - m) + fabsf(gv[k].y - m) +
                      fabsf(gv[k].z - m) + fabsf(gv[k].w - m);
            }
        } else {
            for (int k = 0; k < PT; ++k) {
                long i = base + (long)k * BLOCK;
                if (i < n4) {
                    f32x4 gv = g[i];
                    s2 += fabsf(gv.x - m) + fabsf(gv.y - m) +
                          fabsf(gv.z - m) + fabsf(gv.w - m);
                }
            }
        }
    }
    #pragma unroll
    for (int off = 32; off; off >>= 1) s2 += __shfl_down(s2, off);
    __syncthreads();                    // protect lfa reuse
    if ((tid & 63) == 0) lfa[tid >> 6] = s2;
    __syncthreads();
    if (tid == 0) {
        float bs = lfa[0] + lfa[1] + lfa[2] + lfa[3];
        ws[2 * nblk + blockIdx.x] = (double)bs;
        __threadfence();
    }
    grid.sync();

    // ---------------- finalize: block 0 ----------------
    if (blockIdx.x == 0) {
        double a = 0.0, s = 0.0;
        for (int i = tid; i < nblk; i += BLOCK) {
            a += ws[i];
            s += ws[2 * nblk + i];
        }
        #pragma unroll
        for (int off = 32; off; off >>= 1) {
            a += __shfl_down(a, off);
            s += __shfl_down(s, off);
        }
        if ((tid & 63) == 0) { lda[tid >> 6] = a; lda[4 + (tid >> 6)] = s; }
        __syncthreads();
        if (tid == 0) {
            double ra = lda[0] + lda[1] + lda[2] + lda[3];
            double rs = lda[4] + lda[5] + lda[6] + lda[7];
            out[0] = (float)(ra * inv_n + LAMBD * (rs * inv_n));
        }
    }
}

extern "C" void kernel_launch(void* const* d_in, const int* in_sizes, int n_in,
                              void* d_out, int out_size, void* d_ws, size_t ws_size,
                              hipStream_t stream) {
    const f32x4* r = (const f32x4*)d_in[0];
    const f32x4* g = (const f32x4*)d_in[1];
    const f32x4* t = (const f32x4*)d_in[2];
    float* out = (float*)d_out;
    double* ws = (double*)d_ws;

    int n = in_sizes[0];               // 16777216
    int n4 = n >> 2;                   // 4194304 float4s
    int ntiles = (n4 + TILE - 1) / TILE;   // 2048
    double inv_n = 1.0 / (double)n;

    // clamp grid to co-residency for cooperative launch
    int occ = 8;
    hipOccupancyMaxActiveBlocksPerMultiprocessor(&occ, (const void*)fused_kernel, BLOCK, 0);
    if (occ < 1) occ = 1;
    int grid = occ * 256;              // 256 CUs
    if (grid > ntiles) grid = ntiles;

    void* args[] = {(void*)&r, (void*)&t, (void*)&g, (void*)&ws,
                    (void*)&out, (void*)&n4, (void*)&ntiles, (void*)&inv_n};
    hipLaunchCooperativeKernel((void*)fused_kernel, dim3(grid), dim3(BLOCK),
                               args, 0, stream);
}